// Round 9
// baseline (578.509 us; speedup 1.0000x reference)
//
#include <hip/hip_runtime.h>
#include <hip/hip_cooperative_groups.h>

namespace cg = cooperative_groups;

#define N_NODES 50000
#define N_EDGES 500000
#define IN_C 128
#define HID_C 128
#define OUT_C 64

#define SCAN_NB 196            // (50000+255)/256
#define NTILES 782             // (50000+63)/64
#define SP 136                 // padded LDS row stride (shorts)

typedef short s16x8 __attribute__((ext_vector_type(8)));
typedef float f32x4 __attribute__((ext_vector_type(4)));

__device__ __forceinline__ unsigned short f2bf(float f) {
    unsigned int u = __float_as_uint(f);
    u = (u + 0x7FFF + ((u >> 16) & 1)) >> 16;  // round-to-nearest-even
    return (unsigned short)u;
}
__device__ __forceinline__ float bf2f(unsigned short u) {
    return __uint_as_float(((unsigned int)u) << 16);
}

// ================= phase device functions (shared by mega + fallback) =================

// scan1: per-block inclusive prefix of degi -> rowptr, block sums, dinv
__device__ void scan1_phase(const int* __restrict__ degi, int* __restrict__ rowptr,
                            int* __restrict__ bsum, float* __restrict__ dinv,
                            int bid, int tid, int* sh) {
    const int i = bid * 256 + tid;
    int v = (i < N_NODES) ? degi[i] : 0;
    sh[tid] = v;
    __syncthreads();
#pragma unroll
    for (int off = 1; off < 256; off <<= 1) {
        int tmp = (tid >= off) ? sh[tid - off] : 0;
        __syncthreads();
        sh[tid] += tmp;
        __syncthreads();
    }
    if (i < N_NODES) {
        rowptr[i] = sh[tid];
        dinv[i] = rsqrtf((float)v + 1.0f);
    }
    if (tid == 255) bsum[bid] = sh[255];
}

// scan23: every block redundantly scans the 196 block sums, converts rowptr to
// global exclusive, writes cursor (degi)
__device__ void scan23_phase(int* __restrict__ rowptr, int* __restrict__ degi,
                             const int* __restrict__ bsum, int bid, int tid, int* sh) {
    int v = (tid < SCAN_NB) ? bsum[tid] : 0;
    sh[tid] = v;
    __syncthreads();
#pragma unroll
    for (int off = 1; off < 256; off <<= 1) {
        int tmp = (tid >= off) ? sh[tid - off] : 0;
        __syncthreads();
        sh[tid] += tmp;
        __syncthreads();
    }
    const int myoff = sh[bid] - bsum[bid];  // exclusive prefix of my block
    const int i = bid * 256 + tid;
    if (i < N_NODES) {
        int d = degi[i];
        int ex = rowptr[i] - d + myoff;
        rowptr[i] = ex;
        degi[i] = ex;  // cursor for fill
    }
    if (i == 0) rowptr[N_NODES] = N_EDGES;
}

// GEMM: H[n,NOUT](bf16) = (X[n,128] @ W[128,NOUT]) * (PRESCALE ? dinv[n] : 1)
template <int NOUT, bool XBF16, bool PRESCALE>
__device__ void gemm_phase(const void* __restrict__ Xv, const float* __restrict__ W,
                           const float* __restrict__ dinv, unsigned short* __restrict__ H,
                           int bid, int nblocks, int tid, unsigned short* Xl) {
    constexpr int NT = NOUT / 64;
    const int w = tid >> 6;
    const int lane = tid & 63;
    const int kk = lane >> 4;
    const int cl = lane & 15;

    // W fragments loaded ONCE per phase (invariant across tiles)
    s16x8 bfrag[NT][4];
#pragma unroll
    for (int i = 0; i < NT; i++) {
        int colg = (w * NT + i) * 16 + cl;
#pragma unroll
        for (int s = 0; s < 4; s++)
#pragma unroll
            for (int j = 0; j < 8; j++)
                bfrag[i][s][j] = (short)f2bf(W[(s * 32 + kk * 8 + j) * NOUT + colg]);
    }

    for (int t = bid; t < NTILES; t += nblocks) {
        const int row0 = t * 64;
        __syncthreads();  // protect LDS from previous iteration's readers
        for (int c = tid; c < 64 * 32; c += 256) {
            int r = c >> 5, cc = c & 31;
            int gr = row0 + r;
            ushort4 o;
            if (XBF16) {
                o = (gr < N_NODES) ? ((const ushort4*)Xv)[(size_t)gr * 32 + cc]
                                   : make_ushort4(0, 0, 0, 0);
            } else {
                if (gr < N_NODES) {
                    float4 v = ((const float4*)Xv)[(size_t)gr * 32 + cc];
                    o = make_ushort4(f2bf(v.x), f2bf(v.y), f2bf(v.z), f2bf(v.w));
                } else {
                    o = make_ushort4(0, 0, 0, 0);
                }
            }
            *(ushort4*)&Xl[r * SP + cc * 4] = o;
        }
        __syncthreads();

        f32x4 acc[4][NT];
#pragma unroll
        for (int rt = 0; rt < 4; rt++)
#pragma unroll
            for (int i = 0; i < NT; i++) acc[rt][i] = (f32x4){0.f, 0.f, 0.f, 0.f};

#pragma unroll
        for (int rt = 0; rt < 4; rt++) {
            const int rl = rt * 16 + cl;
            s16x8 a[4];
#pragma unroll
            for (int s = 0; s < 4; s++)
                a[s] = *(const s16x8*)&Xl[rl * SP + s * 32 + kk * 8];
#pragma unroll
            for (int i = 0; i < NT; i++)
#pragma unroll
                for (int s = 0; s < 4; s++)
                    acc[rt][i] = __builtin_amdgcn_mfma_f32_16x16x32_bf16(a[s], bfrag[i][s],
                                                                         acc[rt][i], 0, 0, 0);
        }

#pragma unroll
        for (int rt = 0; rt < 4; rt++) {
            float dvv[4] = {1.f, 1.f, 1.f, 1.f};
            if (PRESCALE) {
                float4 dv = *(const float4*)&dinv[row0 + rt * 16 + kk * 4];
                dvv[0] = dv.x; dvv[1] = dv.y; dvv[2] = dv.z; dvv[3] = dv.w;
            }
#pragma unroll
            for (int i = 0; i < NT; i++) {
                int colg = (w * NT + i) * 16 + cl;
#pragma unroll
                for (int r = 0; r < 4; r++) {
                    int rowg = row0 + rt * 16 + kk * 4 + r;
                    if (rowg < N_NODES)
                        H[(size_t)rowg * NOUT + colg] = f2bf(dvv[r] * acc[rt][i][r]);
                }
            }
        }
    }
}

// agg layer 1 (128 ch, UNSCALED h1): 1 node/wave, half-wave edge split, per-edge dinv[s].
// out[n][c] = relu( dinv[n]*( dinv[n]*h1[n][c] + sum_s dinv[s]*h1[s][c] ) + b[c] )
__device__ void agg128_phase(const int* __restrict__ rowptr, const int* __restrict__ csr,
                             const float* __restrict__ dinv, const uint2* __restrict__ H,
                             const float* __restrict__ b, uint2* __restrict__ out,
                             int bid, int nb, int tid) {
    const int wave0 = bid * 4 + (tid >> 6);
    const int nwaves = nb * 4;
    const int half = (tid >> 5) & 1;
    const int q = tid & 31;

    for (int node = wave0; node < N_NODES; node += nwaves) {
        float a0 = 0.f, a1 = 0.f, a2 = 0.f, a3 = 0.f;
        const int e0 = rowptr[node];
        const int cnt = rowptr[node + 1] - e0;
        const int base = e0 + half * 4;

        int k = 0;
        for (; k + 8 <= cnt; k += 8) {
            int i0 = csr[base + k];
            int i1 = csr[base + k + 1];
            int i2 = csr[base + k + 2];
            int i3 = csr[base + k + 3];
            float d0 = dinv[i0], d1 = dinv[i1], d2 = dinv[i2], d3 = dinv[i3];
            uint2 h0 = H[(size_t)i0 * 32 + q];
            uint2 h1v = H[(size_t)i1 * 32 + q];
            uint2 h2v = H[(size_t)i2 * 32 + q];
            uint2 h3v = H[(size_t)i3 * 32 + q];
            a0 = fmaf(d0, bf2f((unsigned short)(h0.x & 0xffff)), a0);
            a1 = fmaf(d0, bf2f((unsigned short)(h0.x >> 16)), a1);
            a2 = fmaf(d0, bf2f((unsigned short)(h0.y & 0xffff)), a2);
            a3 = fmaf(d0, bf2f((unsigned short)(h0.y >> 16)), a3);
            a0 = fmaf(d1, bf2f((unsigned short)(h1v.x & 0xffff)), a0);
            a1 = fmaf(d1, bf2f((unsigned short)(h1v.x >> 16)), a1);
            a2 = fmaf(d1, bf2f((unsigned short)(h1v.y & 0xffff)), a2);
            a3 = fmaf(d1, bf2f((unsigned short)(h1v.y >> 16)), a3);
            a0 = fmaf(d2, bf2f((unsigned short)(h2v.x & 0xffff)), a0);
            a1 = fmaf(d2, bf2f((unsigned short)(h2v.x >> 16)), a1);
            a2 = fmaf(d2, bf2f((unsigned short)(h2v.y & 0xffff)), a2);
            a3 = fmaf(d2, bf2f((unsigned short)(h2v.y >> 16)), a3);
            a0 = fmaf(d3, bf2f((unsigned short)(h3v.x & 0xffff)), a0);
            a1 = fmaf(d3, bf2f((unsigned short)(h3v.x >> 16)), a1);
            a2 = fmaf(d3, bf2f((unsigned short)(h3v.y & 0xffff)), a2);
            a3 = fmaf(d3, bf2f((unsigned short)(h3v.y >> 16)), a3);
        }
        for (int j = k + half; j < cnt; j += 2) {
            int s = csr[e0 + j];
            float ds = dinv[s];
            uint2 h = H[(size_t)s * 32 + q];
            a0 = fmaf(ds, bf2f((unsigned short)(h.x & 0xffff)), a0);
            a1 = fmaf(ds, bf2f((unsigned short)(h.x >> 16)), a1);
            a2 = fmaf(ds, bf2f((unsigned short)(h.y & 0xffff)), a2);
            a3 = fmaf(ds, bf2f((unsigned short)(h.y >> 16)), a3);
        }

        a0 += __shfl_xor(a0, 32);
        a1 += __shfl_xor(a1, 32);
        a2 += __shfl_xor(a2, 32);
        a3 += __shfl_xor(a3, 32);

        if (half == 0) {
            const float dn = dinv[node];
            uint2 self = H[(size_t)node * 32 + q];
            float4 bb = *(const float4*)&b[q * 4];
            float r0 = fmaf(dn, fmaf(dn, bf2f((unsigned short)(self.x & 0xffff)), a0), bb.x);
            float r1 = fmaf(dn, fmaf(dn, bf2f((unsigned short)(self.x >> 16)), a1), bb.y);
            float r2 = fmaf(dn, fmaf(dn, bf2f((unsigned short)(self.y & 0xffff)), a2), bb.z);
            float r3 = fmaf(dn, fmaf(dn, bf2f((unsigned short)(self.y >> 16)), a3), bb.w);
            r0 = fmaxf(r0, 0.f);
            r1 = fmaxf(r1, 0.f);
            r2 = fmaxf(r2, 0.f);
            r3 = fmaxf(r3, 0.f);
            uint2 o;
            o.x = (unsigned int)f2bf(r0) | ((unsigned int)f2bf(r1) << 16);
            o.y = (unsigned int)f2bf(r2) | ((unsigned int)f2bf(r3) << 16);
            out[(size_t)node * 32 + q] = o;
        }
    }
}

// agg layer 2 (64 ch, h3 PRE-SCALED by dinv): 1 node/wave, fp32 out
__device__ void agg64_phase(const int* __restrict__ rowptr, const int* __restrict__ csr,
                            const float* __restrict__ dinv, const unsigned int* __restrict__ H,
                            const float* __restrict__ b, float2* __restrict__ out,
                            int bid, int nb, int tid) {
    const int wave0 = bid * 4 + (tid >> 6);
    const int nwaves = nb * 4;
    const int half = (tid >> 5) & 1;
    const int q = tid & 31;

    for (int node = wave0; node < N_NODES; node += nwaves) {
        float a0 = 0.f, a1 = 0.f;
        const int e0 = rowptr[node];
        const int cnt = rowptr[node + 1] - e0;
        const int base = e0 + half * 4;

        int k = 0;
        for (; k + 8 <= cnt; k += 8) {
            int i0 = csr[base + k];
            int i1 = csr[base + k + 1];
            int i2 = csr[base + k + 2];
            int i3 = csr[base + k + 3];
            unsigned int h0 = H[(size_t)i0 * 32 + q];
            unsigned int h1 = H[(size_t)i1 * 32 + q];
            unsigned int h2 = H[(size_t)i2 * 32 + q];
            unsigned int h3 = H[(size_t)i3 * 32 + q];
            a0 += bf2f((unsigned short)(h0 & 0xffff)) + bf2f((unsigned short)(h1 & 0xffff)) +
                  bf2f((unsigned short)(h2 & 0xffff)) + bf2f((unsigned short)(h3 & 0xffff));
            a1 += bf2f((unsigned short)(h0 >> 16)) + bf2f((unsigned short)(h1 >> 16)) +
                  bf2f((unsigned short)(h2 >> 16)) + bf2f((unsigned short)(h3 >> 16));
        }
        for (int j = k + half; j < cnt; j += 2) {
            int s = csr[e0 + j];
            unsigned int h = H[(size_t)s * 32 + q];
            a0 += bf2f((unsigned short)(h & 0xffff));
            a1 += bf2f((unsigned short)(h >> 16));
        }

        a0 += __shfl_xor(a0, 32);
        a1 += __shfl_xor(a1, 32);

        if (half == 0) {
            const float dn = dinv[node];
            unsigned int self = H[(size_t)node * 32 + q];
            float2 bb = *(const float2*)&b[q * 2];
            float r0 = fmaf(dn, bf2f((unsigned short)(self & 0xffff)) + a0, bb.x);
            float r1 = fmaf(dn, bf2f((unsigned short)(self >> 16)) + a1, bb.y);
            out[(size_t)node * 32 + q] = make_float2(r0, r1);
        }
    }
}

// ================= cooperative mega-kernel =================

__global__ __launch_bounds__(256, 4) void mega_kernel(
    const float* __restrict__ x, const int* __restrict__ src, const int* __restrict__ dst,
    const float* __restrict__ W1, const float* __restrict__ b1,
    const float* __restrict__ W2, const float* __restrict__ b2,
    unsigned short* __restrict__ h1, unsigned short* __restrict__ h2,
    float* __restrict__ dinv, int* __restrict__ degi, int* __restrict__ rowptr,
    int* __restrict__ csr, int* __restrict__ bsum, float* __restrict__ out) {
    __shared__ unsigned short Xl[64 * SP];  // 17408 B; aliased by scan phases
    int* sh = (int*)Xl;

    cg::grid_group g = cg::this_grid();
    const int bid = blockIdx.x;
    const int nb = gridDim.x;
    const int tid = threadIdx.x;

    // P0: zero degree array
    for (int i = bid * 256 + tid; i < N_NODES; i += nb * 256) degi[i] = 0;
    g.sync();

    // P1: role split — GEMM1 (unscaled h1) || degree histogram
    const int degb = nb >> 3;
    const int gb1 = nb - degb;
    if (bid < gb1) {
        gemm_phase<HID_C, false, false>(x, W1, nullptr, h1, bid, gb1, tid, Xl);
    } else {
        for (int e = (bid - gb1) * 256 + tid; e < N_EDGES; e += degb * 256)
            atomicAdd(&degi[dst[e]], 1);
    }
    g.sync();

    // P2: scan1
    if (bid < SCAN_NB) scan1_phase(degi, rowptr, bsum, dinv, bid, tid, sh);
    g.sync();

    // P3: scan23
    if (bid < SCAN_NB) scan23_phase(rowptr, degi, bsum, bid, tid, sh);
    g.sync();

    // P4: fill CSR
    for (int e = bid * 256 + tid; e < N_EDGES; e += nb * 256) {
        int d = dst[e];
        int pos = atomicAdd(&degi[d], 1);
        csr[pos] = src[e];
    }
    g.sync();

    // P5: agg layer 1 -> h2 (relu'd bf16 activations)
    agg128_phase(rowptr, csr, dinv, (const uint2*)h1, b1, (uint2*)h2, bid, nb, tid);
    g.sync();

    // P6: GEMM2 (pre-scaled by dinv) -> h3 (reuses h1 region)
    gemm_phase<OUT_C, true, true>(h2, W2, dinv, h1, bid, nb, tid, Xl);
    g.sync();

    // P7: agg layer 2 -> out (fp32)
    agg64_phase(rowptr, csr, dinv, (const unsigned int*)h1, b2, (float2*)out, bid, nb, tid);
}

// ================= fallback wrappers (used only if cooperative launch fails) =================

__global__ __launch_bounds__(256) void k_zero(int* __restrict__ p, int n) {
    int i = blockIdx.x * blockDim.x + threadIdx.x;
    if (i < n) p[i] = 0;
}
__global__ void k_deg(const int* __restrict__ dst, int* __restrict__ degi) {
    int e = blockIdx.x * blockDim.x + threadIdx.x;
    if (e < N_EDGES) atomicAdd(&degi[dst[e]], 1);
}
__global__ __launch_bounds__(256) void k_scan1(const int* degi, int* rowptr, int* bsum,
                                               float* dinv) {
    __shared__ int sh[256];
    scan1_phase(degi, rowptr, bsum, dinv, blockIdx.x, threadIdx.x, sh);
}
__global__ __launch_bounds__(256) void k_scan23(int* rowptr, int* degi, const int* bsum) {
    __shared__ int sh[256];
    scan23_phase(rowptr, degi, bsum, blockIdx.x, threadIdx.x, sh);
}
__global__ void k_fill(const int* __restrict__ src, const int* __restrict__ dst,
                       int* __restrict__ cursor, int* __restrict__ csr) {
    int e = blockIdx.x * blockDim.x + threadIdx.x;
    if (e < N_EDGES) {
        int d = dst[e];
        int pos = atomicAdd(&cursor[d], 1);
        csr[pos] = src[e];
    }
}
template <int NOUT, bool XBF16, bool PRESCALE>
__global__ __launch_bounds__(256, 4) void k_gemm(const void* Xv, const float* W,
                                                 const float* dinv, unsigned short* H) {
    __shared__ unsigned short Xl[64 * SP];
    gemm_phase<NOUT, XBF16, PRESCALE>(Xv, W, dinv, H, blockIdx.x, gridDim.x, threadIdx.x, Xl);
}
__global__ __launch_bounds__(256) void k_agg128(const int* rowptr, const int* csr,
                                                const float* dinv, const uint2* H,
                                                const float* b, uint2* out) {
    agg128_phase(rowptr, csr, dinv, H, b, out, blockIdx.x, gridDim.x, threadIdx.x);
}
__global__ __launch_bounds__(256) void k_agg64(const int* rowptr, const int* csr,
                                               const float* dinv, const unsigned int* H,
                                               const float* b, float2* out) {
    agg64_phase(rowptr, csr, dinv, H, b, out, blockIdx.x, gridDim.x, threadIdx.x);
}

// ================= launch =================

extern "C" void kernel_launch(void* const* d_in, const int* in_sizes, int n_in,
                              void* d_out, int out_size, void* d_ws, size_t ws_size,
                              hipStream_t stream) {
    const float* x  = (const float*)d_in[0];
    const int*   ei = (const int*)d_in[1];
    const float* W1 = (const float*)d_in[2];
    const float* b1 = (const float*)d_in[3];
    const float* W2 = (const float*)d_in[4];
    const float* b2 = (const float*)d_in[5];
    const int* src = ei;
    const int* dst = ei + N_EDGES;

    unsigned short* h1 = (unsigned short*)d_ws;                 // [N][128] bf16 (unscaled h1 / h3)
    unsigned short* h2 = h1 + (size_t)N_NODES * HID_C;          // [N][128] bf16 activations
    float* dinv   = (float*)(h2 + (size_t)N_NODES * HID_C);     // 50,048 f
    int*   degi   = (int*)(dinv + 50048);                       // 50,048 i (deg -> cursor)
    int*   rowptr = degi + 50048;                               // 50,001 i
    int*   csr    = rowptr + 50051;                             // 500,000 i
    int*   bsum   = csr + 500000;                               // 256 i
    float* out = (float*)d_out;

    // cooperative mega-kernel path
    int occ = 0;
    hipError_t qerr =
        hipOccupancyMaxActiveBlocksPerMultiprocessor(&occ, (const void*)mega_kernel, 256, 0);
    if (qerr == hipSuccess && occ >= 1) {
        int grid = occ * 256;  // 256 CUs on MI355X
        if (grid > 1024) grid = 1024;
        void* args[] = {(void*)&x,    (void*)&src,  (void*)&dst,  (void*)&W1,
                        (void*)&b1,   (void*)&W2,   (void*)&b2,   (void*)&h1,
                        (void*)&h2,   (void*)&dinv, (void*)&degi, (void*)&rowptr,
                        (void*)&csr,  (void*)&bsum, (void*)&out};
        hipError_t lerr = hipLaunchCooperativeKernel((const void*)mega_kernel, dim3(grid),
                                                     dim3(256), args, 0, stream);
        if (lerr == hipSuccess) return;
    }

    // fallback: multi-kernel path (same phase implementations)
    k_zero<<<SCAN_NB, 256, 0, stream>>>(degi, N_NODES);
    k_deg<<<(N_EDGES + 255) / 256, 256, 0, stream>>>(dst, degi);
    k_scan1<<<SCAN_NB, 256, 0, stream>>>(degi, rowptr, bsum, dinv);
    k_scan23<<<SCAN_NB, 256, 0, stream>>>(rowptr, degi, bsum);
    k_gemm<HID_C, false, false><<<NTILES, 256, 0, stream>>>(x, W1, nullptr, h1);
    k_fill<<<(N_EDGES + 255) / 256, 256, 0, stream>>>(src, dst, degi, csr);
    k_agg128<<<N_NODES / 4, 256, 0, stream>>>(rowptr, csr, dinv, (const uint2*)h1, b1,
                                              (uint2*)h2);
    k_gemm<OUT_C, true, true><<<NTILES, 256, 0, stream>>>(h2, W2, dinv, h1);
    k_agg64<<<N_NODES / 4, 256, 0, stream>>>(rowptr, csr, dinv, (const unsigned int*)h1, b2,
                                             (float2*)out);
}

// Round 10
// 200.155 us; speedup vs baseline: 2.8903x; 2.8903x over previous
//
#include <hip/hip_runtime.h>

#define N_NODES 50000
#define N_EDGES 500000
#define IN_C 128
#define HID_C 128
#define OUT_C 64

#define SCAN_NB 196            // (50000+255)/256
#define NTILES 782             // (50000+63)/64
#define SP 136                 // padded LDS row stride (shorts)

typedef short s16x8 __attribute__((ext_vector_type(8)));
typedef float f32x4 __attribute__((ext_vector_type(4)));

__device__ __forceinline__ unsigned short f2bf(float f) {
    unsigned int u = __float_as_uint(f);
    u = (u + 0x7FFF + ((u >> 16) & 1)) >> 16;  // round-to-nearest-even
    return (unsigned short)u;
}
__device__ __forceinline__ float bf2f(unsigned short u) {
    return __uint_as_float(((unsigned int)u) << 16);
}

// ---------------- zero ----------------

__global__ __launch_bounds__(256) void zero_kernel(int4* __restrict__ p, int n4) {
    int i = blockIdx.x * blockDim.x + threadIdx.x;
    if (i < n4) p[i] = make_int4(0, 0, 0, 0);
}

// ---------------- CSR build ----------------

__global__ void deg_kernel(const int* __restrict__ dst, int* __restrict__ degi) {
    int e = blockIdx.x * blockDim.x + threadIdx.x;
    if (e < N_EDGES) atomicAdd(&degi[dst[e]], 1);
}

__global__ __launch_bounds__(256) void scan1_kernel(const int* __restrict__ degi,
                                                    int* __restrict__ rowptr,
                                                    int* __restrict__ blocksum,
                                                    float* __restrict__ dinv) {
    __shared__ int sh[256];
    const int t = threadIdx.x;
    const int i = blockIdx.x * 256 + t;
    int v = (i < N_NODES) ? degi[i] : 0;
    sh[t] = v;
    __syncthreads();
#pragma unroll
    for (int off = 1; off < 256; off <<= 1) {
        int tmp = (t >= off) ? sh[t - off] : 0;
        __syncthreads();
        sh[t] += tmp;
        __syncthreads();
    }
    if (i < N_NODES) {
        rowptr[i] = sh[t];
        dinv[i] = rsqrtf((float)v + 1.0f);
    }
    if (t == 255) blocksum[blockIdx.x] = sh[255];
}

__global__ __launch_bounds__(256) void scan23_kernel(int* __restrict__ rowptr,
                                                     int* __restrict__ degi,
                                                     const int* __restrict__ blocksum) {
    __shared__ int sh[256];
    const int t = threadIdx.x;
    int v = (t < SCAN_NB) ? blocksum[t] : 0;
    sh[t] = v;
    __syncthreads();
#pragma unroll
    for (int off = 1; off < 256; off <<= 1) {
        int tmp = (t >= off) ? sh[t - off] : 0;
        __syncthreads();
        sh[t] += tmp;
        __syncthreads();
    }
    const int myoff = sh[blockIdx.x] - blocksum[blockIdx.x];
    const int i = blockIdx.x * 256 + t;
    if (i < N_NODES) {
        int d = degi[i];
        int ex = rowptr[i] - d + myoff;
        rowptr[i] = ex;
        degi[i] = ex;  // cursor for fill
    }
    if (i == 0) rowptr[N_NODES] = N_EDGES;
}

__global__ void fill_kernel(const int* __restrict__ src, const int* __restrict__ dst,
                            int* __restrict__ cursor, int* __restrict__ csr_src) {
    int e = blockIdx.x * blockDim.x + threadIdx.x;
    if (e < N_EDGES) {
        int d = dst[e];
        int pos = atomicAdd(&cursor[d], 1);
        csr_src[pos] = src[e];
    }
}

// ---------------- MFMA GEMM: H(chunked bf16 [NOUT/32][N][32]) = dinv[n]*(X @ W) ----------------
// XBF16 input (layer 2) is chunked [IN/32][N][32]; fp32 input (layer 1) is row-major.

template <int NOUT, bool XBF16>
__global__ __launch_bounds__(256) void mfma_gemm(const void* __restrict__ Xv,
                                                 const float* __restrict__ W,
                                                 const float* __restrict__ dinv,
                                                 unsigned short* __restrict__ H, int nrows) {
    constexpr int NT = NOUT / 64;
    __shared__ unsigned short Xl[64 * SP];

    const int tid = threadIdx.x;
    const int w = tid >> 6;
    const int lane = tid & 63;
    const int kk = lane >> 4;
    const int cl = lane & 15;
    const int row0 = blockIdx.x * 64;

    for (int c = tid; c < 64 * 32; c += 256) {
        int r = c >> 5, cc = c & 31;  // cc: ushort4 index within 128-ch row
        int gr = row0 + r;
        ushort4 o;
        if (XBF16) {
            if (gr < nrows) {
                int ckk = cc >> 3;  // input chunk (32 ch = 8 ushort4)
                o = ((const ushort4*)Xv)[((size_t)ckk * N_NODES + gr) * 8 + (cc & 7)];
            } else {
                o = make_ushort4(0, 0, 0, 0);
            }
        } else {
            if (gr < nrows) {
                float4 v = ((const float4*)Xv)[(size_t)gr * 32 + cc];
                o = make_ushort4(f2bf(v.x), f2bf(v.y), f2bf(v.z), f2bf(v.w));
            } else {
                o = make_ushort4(0, 0, 0, 0);
            }
        }
        *(ushort4*)&Xl[r * SP + cc * 4] = o;
    }

    s16x8 bfrag[NT][4];
#pragma unroll
    for (int i = 0; i < NT; i++) {
        int colg = (w * NT + i) * 16 + cl;
#pragma unroll
        for (int s = 0; s < 4; s++)
#pragma unroll
            for (int j = 0; j < 8; j++)
                bfrag[i][s][j] = (short)f2bf(W[(s * 32 + kk * 8 + j) * NOUT + colg]);
    }

    __syncthreads();

    f32x4 acc[4][NT];
#pragma unroll
    for (int rt = 0; rt < 4; rt++)
#pragma unroll
        for (int i = 0; i < NT; i++) acc[rt][i] = (f32x4){0.f, 0.f, 0.f, 0.f};

#pragma unroll
    for (int rt = 0; rt < 4; rt++) {
        const int rl = rt * 16 + cl;
        s16x8 a[4];
#pragma unroll
        for (int s = 0; s < 4; s++)
            a[s] = *(const s16x8*)&Xl[rl * SP + s * 32 + kk * 8];
#pragma unroll
        for (int i = 0; i < NT; i++)
#pragma unroll
            for (int s = 0; s < 4; s++)
                acc[rt][i] = __builtin_amdgcn_mfma_f32_16x16x32_bf16(a[s], bfrag[i][s],
                                                                     acc[rt][i], 0, 0, 0);
    }

#pragma unroll
    for (int rt = 0; rt < 4; rt++) {
        float4 dv = *(const float4*)&dinv[row0 + rt * 16 + kk * 4];
        float dvv[4] = {dv.x, dv.y, dv.z, dv.w};
#pragma unroll
        for (int i = 0; i < NT; i++) {
            int colg = (w * NT + i) * 16 + cl;
            int ckk = colg >> 5;
            int cw = colg & 31;
#pragma unroll
            for (int r = 0; r < 4; r++) {
                int rowg = row0 + rt * 16 + kk * 4 + r;
                if (rowg < nrows)
                    H[((size_t)ckk * N_NODES + rowg) * 32 + cw] = f2bf(dvv[r] * acc[rt][i][r]);
            }
        }
    }
}

// ---------------- chunked agg, ONE NODE PER WAVE (wave-uniform edge loop) ----------------
// H pre-scaled bf16 chunked [NCK][N][32]. Wave lanes = 4 edge-slots x 16 channel-lanes.
// Chunk pinned to an XCD set via blockIdx&7 (round-robin dispatch): ck = (bid&7)/XPC.
// Each XCD's 4MB L2 then holds its 3.2MB chunk -> gathers become L2 hits.
// out[n][c] = (relu?)( dinv[n]*(H'[n][c] + sum_s H'[s][c]) + b[c] )

// layer 1: 4 chunks (128 ch), XPC=2, bf16 chunked output, ReLU
__global__ __launch_bounds__(256) void agg1c_kernel(const int* __restrict__ rowptr,
                                                    const int* __restrict__ csr,
                                                    const float* __restrict__ dinv,
                                                    const unsigned int* __restrict__ H,
                                                    const float* __restrict__ b,
                                                    unsigned int* __restrict__ out) {
    const int xcd = blockIdx.x & 7;
    const int ck = xcd >> 1;                              // 4 chunks, 2 XCDs each
    const int g = (blockIdx.x >> 3) * 2 + (xcd & 1);      // node-group within chunk
    const int node = g * 4 + (threadIdx.x >> 6);
    if (node >= N_NODES) return;
    const int slot = (threadIdx.x >> 4) & 3;
    const int ch = threadIdx.x & 15;

    const unsigned int* __restrict__ Hc = H + (size_t)ck * N_NODES * 16;

    const int e0 = rowptr[node];
    const int cnt = rowptr[node + 1] - e0;

    float a0 = 0.f, a1 = 0.f;
    for (int k = slot; k < cnt; k += 4) {  // trip counts differ by <=1 across slots
        int s = csr[e0 + k];
        unsigned int h = Hc[(size_t)s * 16 + ch];
        a0 += bf2f((unsigned short)(h & 0xffff));
        a1 += bf2f((unsigned short)(h >> 16));
    }
    a0 += __shfl_xor(a0, 16);
    a0 += __shfl_xor(a0, 32);
    a1 += __shfl_xor(a1, 16);
    a1 += __shfl_xor(a1, 32);

    if (slot == 0) {
        const float dn = dinv[node];
        unsigned int self = Hc[(size_t)node * 16 + ch];
        float2 bb = ((const float2*)b)[ck * 16 + ch];
        float r0 = fmaf(dn, bf2f((unsigned short)(self & 0xffff)) + a0, bb.x);
        float r1 = fmaf(dn, bf2f((unsigned short)(self >> 16)) + a1, bb.y);
        r0 = fmaxf(r0, 0.f);
        r1 = fmaxf(r1, 0.f);
        out[((size_t)ck * N_NODES + node) * 16 + ch] =
            (unsigned int)f2bf(r0) | ((unsigned int)f2bf(r1) << 16);
    }
}

// layer 2: 2 chunks (64 ch), XPC=4, fp32 row-major output
__global__ __launch_bounds__(256) void agg2c_kernel(const int* __restrict__ rowptr,
                                                    const int* __restrict__ csr,
                                                    const float* __restrict__ dinv,
                                                    const unsigned int* __restrict__ H,
                                                    const float* __restrict__ b,
                                                    float2* __restrict__ out) {
    const int xcd = blockIdx.x & 7;
    const int ck = xcd >> 2;                              // 2 chunks, 4 XCDs each
    const int g = (blockIdx.x >> 3) * 4 + (xcd & 3);
    const int node = g * 4 + (threadIdx.x >> 6);
    if (node >= N_NODES) return;
    const int slot = (threadIdx.x >> 4) & 3;
    const int ch = threadIdx.x & 15;

    const unsigned int* __restrict__ Hc = H + (size_t)ck * N_NODES * 16;

    const int e0 = rowptr[node];
    const int cnt = rowptr[node + 1] - e0;

    float a0 = 0.f, a1 = 0.f;
    for (int k = slot; k < cnt; k += 4) {
        int s = csr[e0 + k];
        unsigned int h = Hc[(size_t)s * 16 + ch];
        a0 += bf2f((unsigned short)(h & 0xffff));
        a1 += bf2f((unsigned short)(h >> 16));
    }
    a0 += __shfl_xor(a0, 16);
    a0 += __shfl_xor(a0, 32);
    a1 += __shfl_xor(a1, 16);
    a1 += __shfl_xor(a1, 32);

    if (slot == 0) {
        const float dn = dinv[node];
        unsigned int self = Hc[(size_t)node * 16 + ch];
        float2 bb = ((const float2*)b)[ck * 16 + ch];
        float r0 = fmaf(dn, bf2f((unsigned short)(self & 0xffff)) + a0, bb.x);
        float r1 = fmaf(dn, bf2f((unsigned short)(self >> 16)) + a1, bb.y);
        out[(size_t)node * 32 + ck * 16 + ch] = make_float2(r0, r1);
    }
}

// ---------------- launch ----------------

extern "C" void kernel_launch(void* const* d_in, const int* in_sizes, int n_in,
                              void* d_out, int out_size, void* d_ws, size_t ws_size,
                              hipStream_t stream) {
    const float* x  = (const float*)d_in[0];
    const int*   ei = (const int*)d_in[1];
    const float* W1 = (const float*)d_in[2];
    const float* b1 = (const float*)d_in[3];
    const float* W2 = (const float*)d_in[4];
    const float* b2 = (const float*)d_in[5];

    const int* src = ei;
    const int* dst = ei + N_EDGES;

    // workspace layout
    unsigned short* h1 = (unsigned short*)d_ws;                 // [4][N][32] bf16 (pre-scaled)
    unsigned short* h2 = h1 + (size_t)N_NODES * HID_C;          // [4][N][32] bf16 activations
    float* dinv   = (float*)(h2 + (size_t)N_NODES * HID_C);     // 50,048 f
    int*   degi   = (int*)(dinv + 50048);                       // 50,048 i (deg -> cursor)
    int*   rowptr = degi + 50048;                               // 50,001 i
    int*   csr    = rowptr + 50051;                             // 500,000 i
    int*   bsum   = csr + 500000;                               // 256 i
    unsigned short* h3 = h1;                                    // reuse h1: [2][N][32] bf16

    // --- CSR build ---
    {
        int n4 = (N_NODES + 3) / 4;
        zero_kernel<<<(n4 + 255) / 256, 256, 0, stream>>>((int4*)degi, n4);
    }
    deg_kernel<<<(N_EDGES + 255) / 256, 256, 0, stream>>>(dst, degi);
    scan1_kernel<<<SCAN_NB, 256, 0, stream>>>(degi, rowptr, bsum, dinv);
    scan23_kernel<<<SCAN_NB, 256, 0, stream>>>(rowptr, degi, bsum);
    fill_kernel<<<(N_EDGES + 255) / 256, 256, 0, stream>>>(src, dst, degi, csr);

    // --- layer 1 ---  (h1: 4 chunks, 2 XCDs each)
    mfma_gemm<HID_C, false><<<NTILES, 256, 0, stream>>>(x, W1, dinv, h1, N_NODES);
    agg1c_kernel<<<8 * 6250, 256, 0, stream>>>(rowptr, csr, dinv, (const unsigned int*)h1, b1,
                                               (unsigned int*)h2);

    // --- layer 2 ---  (h3: 2 chunks, 4 XCDs each)
    mfma_gemm<OUT_C, true><<<NTILES, 256, 0, stream>>>(h2, W2, dinv, h3, N_NODES);
    agg2c_kernel<<<8 * 3125, 256, 0, stream>>>(rowptr, csr, dinv, (const unsigned int*)h3, b2,
                                               (float2*)d_out);
}

// Round 11
// 185.532 us; speedup vs baseline: 3.1181x; 1.0788x over previous
//
#include <hip/hip_runtime.h>

#define N_NODES 50000
#define N_EDGES 500000
#define IN_C 128
#define HID_C 128
#define OUT_C 64

#define SCAN_NB 196            // (50000+255)/256
#define NTILES 782             // (50000+63)/64
#define SP 136                 // padded LDS row stride (shorts)

typedef short s16x8 __attribute__((ext_vector_type(8)));
typedef float f32x4 __attribute__((ext_vector_type(4)));

__device__ __forceinline__ unsigned short f2bf(float f) {
    unsigned int u = __float_as_uint(f);
    u = (u + 0x7FFF + ((u >> 16) & 1)) >> 16;  // round-to-nearest-even
    return (unsigned short)u;
}
__device__ __forceinline__ float bf2f(unsigned short u) {
    return __uint_as_float(((unsigned int)u) << 16);
}

// ---------------- zero ----------------

__global__ __launch_bounds__(256) void zero_kernel(int4* __restrict__ p, int n4) {
    int i = blockIdx.x * blockDim.x + threadIdx.x;
    if (i < n4) p[i] = make_int4(0, 0, 0, 0);
}

// ---------------- CSR build ----------------

__global__ void deg_kernel(const int* __restrict__ dst, int* __restrict__ degi) {
    int e = blockIdx.x * blockDim.x + threadIdx.x;
    if (e < N_EDGES) atomicAdd(&degi[dst[e]], 1);
}

__global__ __launch_bounds__(256) void scan1_kernel(const int* __restrict__ degi,
                                                    int* __restrict__ rowptr,
                                                    int* __restrict__ blocksum,
                                                    float* __restrict__ dinv) {
    __shared__ int sh[256];
    const int t = threadIdx.x;
    const int i = blockIdx.x * 256 + t;
    int v = (i < N_NODES) ? degi[i] : 0;
    sh[t] = v;
    __syncthreads();
#pragma unroll
    for (int off = 1; off < 256; off <<= 1) {
        int tmp = (t >= off) ? sh[t - off] : 0;
        __syncthreads();
        sh[t] += tmp;
        __syncthreads();
    }
    if (i < N_NODES) {
        rowptr[i] = sh[t];
        dinv[i] = rsqrtf((float)v + 1.0f);
    }
    if (t == 255) blocksum[blockIdx.x] = sh[255];
}

__global__ __launch_bounds__(256) void scan23_kernel(int* __restrict__ rowptr,
                                                     int* __restrict__ degi,
                                                     const int* __restrict__ blocksum) {
    __shared__ int sh[256];
    const int t = threadIdx.x;
    int v = (t < SCAN_NB) ? blocksum[t] : 0;
    sh[t] = v;
    __syncthreads();
#pragma unroll
    for (int off = 1; off < 256; off <<= 1) {
        int tmp = (t >= off) ? sh[t - off] : 0;
        __syncthreads();
        sh[t] += tmp;
        __syncthreads();
    }
    const int myoff = sh[blockIdx.x] - blocksum[blockIdx.x];
    const int i = blockIdx.x * 256 + t;
    if (i < N_NODES) {
        int d = degi[i];
        int ex = rowptr[i] - d + myoff;
        rowptr[i] = ex;
        degi[i] = ex;  // cursor for fill
    }
    if (i == 0) rowptr[N_NODES] = N_EDGES;
}

__global__ void fill_kernel(const int* __restrict__ src, const int* __restrict__ dst,
                            int* __restrict__ cursor, int* __restrict__ csr_src) {
    int e = blockIdx.x * blockDim.x + threadIdx.x;
    if (e < N_EDGES) {
        int d = dst[e];
        int pos = atomicAdd(&cursor[d], 1);
        csr_src[pos] = src[e];
    }
}

// ---------------- MFMA GEMM: H(chunked bf16 [NOUT/32][N][32]) = dinv[n]*(X @ W) ----------------
// XBF16 input (layer 2) is chunked [IN/32][N][32]; fp32 input (layer 1) is row-major.

template <int NOUT, bool XBF16>
__global__ __launch_bounds__(256) void mfma_gemm(const void* __restrict__ Xv,
                                                 const float* __restrict__ W,
                                                 const float* __restrict__ dinv,
                                                 unsigned short* __restrict__ H, int nrows) {
    constexpr int NT = NOUT / 64;
    __shared__ unsigned short Xl[64 * SP];

    const int tid = threadIdx.x;
    const int w = tid >> 6;
    const int lane = tid & 63;
    const int kk = lane >> 4;
    const int cl = lane & 15;
    const int row0 = blockIdx.x * 64;

    for (int c = tid; c < 64 * 32; c += 256) {
        int r = c >> 5, cc = c & 31;  // cc: ushort4 index within 128-ch row
        int gr = row0 + r;
        ushort4 o;
        if (XBF16) {
            if (gr < nrows) {
                int ckk = cc >> 3;  // input chunk (32 ch = 8 ushort4)
                o = ((const ushort4*)Xv)[((size_t)ckk * N_NODES + gr) * 8 + (cc & 7)];
            } else {
                o = make_ushort4(0, 0, 0, 0);
            }
        } else {
            if (gr < nrows) {
                float4 v = ((const float4*)Xv)[(size_t)gr * 32 + cc];
                o = make_ushort4(f2bf(v.x), f2bf(v.y), f2bf(v.z), f2bf(v.w));
            } else {
                o = make_ushort4(0, 0, 0, 0);
            }
        }
        *(ushort4*)&Xl[r * SP + cc * 4] = o;
    }

    s16x8 bfrag[NT][4];
#pragma unroll
    for (int i = 0; i < NT; i++) {
        int colg = (w * NT + i) * 16 + cl;
#pragma unroll
        for (int s = 0; s < 4; s++)
#pragma unroll
            for (int j = 0; j < 8; j++)
                bfrag[i][s][j] = (short)f2bf(W[(s * 32 + kk * 8 + j) * NOUT + colg]);
    }

    __syncthreads();

    f32x4 acc[4][NT];
#pragma unroll
    for (int rt = 0; rt < 4; rt++)
#pragma unroll
        for (int i = 0; i < NT; i++) acc[rt][i] = (f32x4){0.f, 0.f, 0.f, 0.f};

#pragma unroll
    for (int rt = 0; rt < 4; rt++) {
        const int rl = rt * 16 + cl;
        s16x8 a[4];
#pragma unroll
        for (int s = 0; s < 4; s++)
            a[s] = *(const s16x8*)&Xl[rl * SP + s * 32 + kk * 8];
#pragma unroll
        for (int i = 0; i < NT; i++)
#pragma unroll
            for (int s = 0; s < 4; s++)
                acc[rt][i] = __builtin_amdgcn_mfma_f32_16x16x32_bf16(a[s], bfrag[i][s],
                                                                     acc[rt][i], 0, 0, 0);
    }

#pragma unroll
    for (int rt = 0; rt < 4; rt++) {
        float4 dv = *(const float4*)&dinv[row0 + rt * 16 + kk * 4];
        float dvv[4] = {dv.x, dv.y, dv.z, dv.w};
#pragma unroll
        for (int i = 0; i < NT; i++) {
            int colg = (w * NT + i) * 16 + cl;
            int ckk = colg >> 5;
            int cw = colg & 31;
#pragma unroll
            for (int r = 0; r < 4; r++) {
                int rowg = row0 + rt * 16 + kk * 4 + r;
                if (rowg < nrows)
                    H[((size_t)ckk * N_NODES + rowg) * 32 + cw] = f2bf(dvv[r] * acc[rt][i][r]);
            }
        }
    }
}

// ---------------- chunked agg, 1 node/wave, 8 edge-slots x 8 ch-lanes x uint2(8B) ----------------
// H pre-scaled bf16 chunked [NCK][N][32] (64B rows = 8 uint2). Chunk pinned to an XCD set via
// blockIdx&7 round-robin -> each chunk's 3.2MB table is L2-resident (R10: FETCH 124->24.5MB).
// 8B/lane restores R8's load-instruction count; 8 edges in flight per wave.
// out[n][c] = (relu?)( dinv[n]*(H'[n][c] + sum_s H'[s][c]) + b[c] )

// layer 1: 4 chunks (128 ch), 2 XCDs/chunk, bf16 chunked output, ReLU
__global__ __launch_bounds__(256) void agg1c_kernel(const int* __restrict__ rowptr,
                                                    const int* __restrict__ csr,
                                                    const float* __restrict__ dinv,
                                                    const uint2* __restrict__ H,
                                                    const float* __restrict__ b,
                                                    uint2* __restrict__ out) {
    const int xcd = blockIdx.x & 7;
    const int ck = xcd >> 1;                          // 4 chunks, 2 XCDs each
    const int g = (blockIdx.x >> 3) * 2 + (xcd & 1);  // node-group [0,12500)
    const int node = g * 4 + (threadIdx.x >> 6);
    if (node >= N_NODES) return;
    const int lane = threadIdx.x & 63;
    const int slot = lane >> 3;  // 0..7 edge slot
    const int ch = lane & 7;     // 0..7 uint2 lane (channels ch*4..ch*4+3)

    const uint2* __restrict__ Hc = H + (size_t)ck * N_NODES * 8;

    const int e0 = rowptr[node];
    const int cnt = rowptr[node + 1] - e0;

    float a0 = 0.f, a1 = 0.f, a2 = 0.f, a3 = 0.f;
    for (int k = slot; k < cnt; k += 8) {  // trip counts differ by <=1 across slots
        int s = csr[e0 + k];
        uint2 h = Hc[(size_t)s * 8 + ch];
        a0 += bf2f((unsigned short)(h.x & 0xffff));
        a1 += bf2f((unsigned short)(h.x >> 16));
        a2 += bf2f((unsigned short)(h.y & 0xffff));
        a3 += bf2f((unsigned short)(h.y >> 16));
    }
    // reduce over slot bits (lane bits 3..5)
    a0 += __shfl_xor(a0, 8);  a1 += __shfl_xor(a1, 8);
    a2 += __shfl_xor(a2, 8);  a3 += __shfl_xor(a3, 8);
    a0 += __shfl_xor(a0, 16); a1 += __shfl_xor(a1, 16);
    a2 += __shfl_xor(a2, 16); a3 += __shfl_xor(a3, 16);
    a0 += __shfl_xor(a0, 32); a1 += __shfl_xor(a1, 32);
    a2 += __shfl_xor(a2, 32); a3 += __shfl_xor(a3, 32);

    if (slot == 0) {
        const float dn = dinv[node];
        uint2 self = Hc[(size_t)node * 8 + ch];
        float4 bb = ((const float4*)b)[ck * 8 + ch];
        float r0 = fmaf(dn, bf2f((unsigned short)(self.x & 0xffff)) + a0, bb.x);
        float r1 = fmaf(dn, bf2f((unsigned short)(self.x >> 16)) + a1, bb.y);
        float r2 = fmaf(dn, bf2f((unsigned short)(self.y & 0xffff)) + a2, bb.z);
        float r3 = fmaf(dn, bf2f((unsigned short)(self.y >> 16)) + a3, bb.w);
        r0 = fmaxf(r0, 0.f);
        r1 = fmaxf(r1, 0.f);
        r2 = fmaxf(r2, 0.f);
        r3 = fmaxf(r3, 0.f);
        uint2 o;
        o.x = (unsigned int)f2bf(r0) | ((unsigned int)f2bf(r1) << 16);
        o.y = (unsigned int)f2bf(r2) | ((unsigned int)f2bf(r3) << 16);
        out[((size_t)ck * N_NODES + node) * 8 + ch] = o;
    }
}

// layer 2: 2 chunks (64 ch), 4 XCDs/chunk, fp32 row-major output
__global__ __launch_bounds__(256) void agg2c_kernel(const int* __restrict__ rowptr,
                                                    const int* __restrict__ csr,
                                                    const float* __restrict__ dinv,
                                                    const uint2* __restrict__ H,
                                                    const float* __restrict__ b,
                                                    float* __restrict__ out) {
    const int xcd = blockIdx.x & 7;
    const int ck = xcd >> 2;                          // 2 chunks, 4 XCDs each
    const int g = (blockIdx.x >> 3) * 4 + (xcd & 3);  // node-group [0,12500)
    const int node = g * 4 + (threadIdx.x >> 6);
    if (node >= N_NODES) return;
    const int lane = threadIdx.x & 63;
    const int slot = lane >> 3;
    const int ch = lane & 7;

    const uint2* __restrict__ Hc = H + (size_t)ck * N_NODES * 8;

    const int e0 = rowptr[node];
    const int cnt = rowptr[node + 1] - e0;

    float a0 = 0.f, a1 = 0.f, a2 = 0.f, a3 = 0.f;
    for (int k = slot; k < cnt; k += 8) {
        int s = csr[e0 + k];
        uint2 h = Hc[(size_t)s * 8 + ch];
        a0 += bf2f((unsigned short)(h.x & 0xffff));
        a1 += bf2f((unsigned short)(h.x >> 16));
        a2 += bf2f((unsigned short)(h.y & 0xffff));
        a3 += bf2f((unsigned short)(h.y >> 16));
    }
    a0 += __shfl_xor(a0, 8);  a1 += __shfl_xor(a1, 8);
    a2 += __shfl_xor(a2, 8);  a3 += __shfl_xor(a3, 8);
    a0 += __shfl_xor(a0, 16); a1 += __shfl_xor(a1, 16);
    a2 += __shfl_xor(a2, 16); a3 += __shfl_xor(a3, 16);
    a0 += __shfl_xor(a0, 32); a1 += __shfl_xor(a1, 32);
    a2 += __shfl_xor(a2, 32); a3 += __shfl_xor(a3, 32);

    if (slot == 0) {
        const float dn = dinv[node];
        uint2 self = Hc[(size_t)node * 8 + ch];
        float4 bb = ((const float4*)b)[ck * 8 + ch];
        float4 r;
        r.x = fmaf(dn, bf2f((unsigned short)(self.x & 0xffff)) + a0, bb.x);
        r.y = fmaf(dn, bf2f((unsigned short)(self.x >> 16)) + a1, bb.y);
        r.z = fmaf(dn, bf2f((unsigned short)(self.y & 0xffff)) + a2, bb.z);
        r.w = fmaf(dn, bf2f((unsigned short)(self.y >> 16)) + a3, bb.w);
        ((float4*)(out + (size_t)node * OUT_C + ck * 32))[ch] = r;
    }
}

// ---------------- launch ----------------

extern "C" void kernel_launch(void* const* d_in, const int* in_sizes, int n_in,
                              void* d_out, int out_size, void* d_ws, size_t ws_size,
                              hipStream_t stream) {
    const float* x  = (const float*)d_in[0];
    const int*   ei = (const int*)d_in[1];
    const float* W1 = (const float*)d_in[2];
    const float* b1 = (const float*)d_in[3];
    const float* W2 = (const float*)d_in[4];
    const float* b2 = (const float*)d_in[5];

    const int* src = ei;
    const int* dst = ei + N_EDGES;

    // workspace layout
    unsigned short* h1 = (unsigned short*)d_ws;                 // [4][N][32] bf16 (pre-scaled)
    unsigned short* h2 = h1 + (size_t)N_NODES * HID_C;          // [4][N][32] bf16 activations
    float* dinv   = (float*)(h2 + (size_t)N_NODES * HID_C);     // 50,048 f
    int*   degi   = (int*)(dinv + 50048);                       // 50,048 i (deg -> cursor)
    int*   rowptr = degi + 50048;                               // 50,001 i
    int*   csr    = rowptr + 50051;                             // 500,000 i
    int*   bsum   = csr + 500000;                               // 256 i
    unsigned short* h3 = h1;                                    // reuse h1: [2][N][32] bf16

    // --- CSR build ---
    {
        int n4 = (N_NODES + 3) / 4;
        zero_kernel<<<(n4 + 255) / 256, 256, 0, stream>>>((int4*)degi, n4);
    }
    deg_kernel<<<(N_EDGES + 255) / 256, 256, 0, stream>>>(dst, degi);
    scan1_kernel<<<SCAN_NB, 256, 0, stream>>>(degi, rowptr, bsum, dinv);
    scan23_kernel<<<SCAN_NB, 256, 0, stream>>>(rowptr, degi, bsum);
    fill_kernel<<<(N_EDGES + 255) / 256, 256, 0, stream>>>(src, dst, degi, csr);

    // --- layer 1 ---  (h1: 4 chunks, 2 XCDs each)
    mfma_gemm<HID_C, false><<<NTILES, 256, 0, stream>>>(x, W1, dinv, h1, N_NODES);
    agg1c_kernel<<<8 * 6250, 256, 0, stream>>>(rowptr, csr, dinv, (const uint2*)h1, b1,
                                               (uint2*)h2);

    // --- layer 2 ---  (h3: 2 chunks, 4 XCDs each)
    mfma_gemm<OUT_C, true><<<NTILES, 256, 0, stream>>>(h2, W2, dinv, h3, N_NODES);
    agg2c_kernel<<<8 * 3125, 256, 0, stream>>>(rowptr, csr, dinv, (const uint2*)h3, b2,
                                               (float*)d_out);
}

// Round 12
// 131.298 us; speedup vs baseline: 4.4061x; 1.4131x over previous
//
#include <hip/hip_runtime.h>

#define N_NODES 50000
#define N_EDGES 500000
#define IN_C 128
#define HID_C 128
#define OUT_C 64

#define SCAN_NB 196            // (50000+255)/256
#define NTILES 782             // (50000+63)/64
#define DEGB 256               // histogram blocks fused into gemm1 dispatch
#define SP 136                 // padded LDS row stride (shorts)

typedef short s16x8 __attribute__((ext_vector_type(8)));
typedef float f32x4 __attribute__((ext_vector_type(4)));

__device__ __forceinline__ unsigned short f2bf(float f) {
    unsigned int u = __float_as_uint(f);
    u = (u + 0x7FFF + ((u >> 16) & 1)) >> 16;  // round-to-nearest-even
    return (unsigned short)u;
}
__device__ __forceinline__ float bf2f(unsigned short u) {
    return __uint_as_float(((unsigned int)u) << 16);
}

// ---------------- zero ----------------

__global__ __launch_bounds__(256) void zero_kernel(int4* __restrict__ p, int n4) {
    int i = blockIdx.x * blockDim.x + threadIdx.x;
    if (i < n4) p[i] = make_int4(0, 0, 0, 0);
}

// ---------------- CSR build ----------------

__global__ __launch_bounds__(256) void scan1_kernel(const int* __restrict__ degi,
                                                    int* __restrict__ rowptr,
                                                    int* __restrict__ blocksum,
                                                    float* __restrict__ dinv) {
    __shared__ int sh[256];
    const int t = threadIdx.x;
    const int i = blockIdx.x * 256 + t;
    int v = (i < N_NODES) ? degi[i] : 0;
    sh[t] = v;
    __syncthreads();
#pragma unroll
    for (int off = 1; off < 256; off <<= 1) {
        int tmp = (t >= off) ? sh[t - off] : 0;
        __syncthreads();
        sh[t] += tmp;
        __syncthreads();
    }
    if (i < N_NODES) {
        rowptr[i] = sh[t];
        dinv[i] = rsqrtf((float)v + 1.0f);
    }
    if (t == 255) blocksum[blockIdx.x] = sh[255];
}

__global__ __launch_bounds__(256) void scan23_kernel(int* __restrict__ rowptr,
                                                     int* __restrict__ degi,
                                                     const int* __restrict__ blocksum) {
    __shared__ int sh[256];
    const int t = threadIdx.x;
    int v = (t < SCAN_NB) ? blocksum[t] : 0;
    sh[t] = v;
    __syncthreads();
#pragma unroll
    for (int off = 1; off < 256; off <<= 1) {
        int tmp = (t >= off) ? sh[t - off] : 0;
        __syncthreads();
        sh[t] += tmp;
        __syncthreads();
    }
    const int myoff = sh[blockIdx.x] - blocksum[blockIdx.x];
    const int i = blockIdx.x * 256 + t;
    if (i < N_NODES) {
        int d = degi[i];
        int ex = rowptr[i] - d + myoff;
        rowptr[i] = ex;
        degi[i] = ex;  // cursor for fill
    }
    if (i == 0) rowptr[N_NODES] = N_EDGES;
}

__global__ void fill_kernel(const int* __restrict__ src, const int* __restrict__ dst,
                            int* __restrict__ cursor, int* __restrict__ csr_src) {
    int e = blockIdx.x * blockDim.x + threadIdx.x;
    if (e < N_EDGES) {
        int d = dst[e];
        int pos = atomicAdd(&cursor[d], 1);
        csr_src[pos] = src[e];
    }
}

// ---------------- MFMA GEMM: H[n,NOUT](bf16) = (X[n,128] @ W[128,NOUT]) * (dinv?) ----------------
// DEG_FUSE: blocks >= NTILES instead run the degree histogram (independent work,
// no ordering needed -> single dispatch replaces gemm1 + deg, hiding ~7us + one gap).

template <int NOUT, bool XBF16, bool PRESCALE, bool DEG_FUSE>
__global__ __launch_bounds__(256) void mfma_gemm(const void* __restrict__ Xv,
                                                 const float* __restrict__ W,
                                                 const float* __restrict__ dinv,
                                                 unsigned short* __restrict__ H,
                                                 const int* __restrict__ dst,
                                                 int* __restrict__ degi) {
    constexpr int NT = NOUT / 64;
    __shared__ unsigned short Xl[64 * SP];

    const int tid = threadIdx.x;

    if (DEG_FUSE && blockIdx.x >= NTILES) {
        for (int e = (blockIdx.x - NTILES) * 256 + tid; e < N_EDGES; e += DEGB * 256)
            atomicAdd(&degi[dst[e]], 1);
        return;
    }

    const int w = tid >> 6;
    const int lane = tid & 63;
    const int kk = lane >> 4;
    const int cl = lane & 15;
    const int row0 = blockIdx.x * 64;

    for (int c = tid; c < 64 * 32; c += 256) {
        int r = c >> 5, cc = c & 31;
        int gr = row0 + r;
        ushort4 o;
        if (XBF16) {
            o = (gr < N_NODES) ? ((const ushort4*)Xv)[(size_t)gr * 32 + cc]
                               : make_ushort4(0, 0, 0, 0);
        } else {
            if (gr < N_NODES) {
                float4 v = ((const float4*)Xv)[(size_t)gr * 32 + cc];
                o = make_ushort4(f2bf(v.x), f2bf(v.y), f2bf(v.z), f2bf(v.w));
            } else {
                o = make_ushort4(0, 0, 0, 0);
            }
        }
        *(ushort4*)&Xl[r * SP + cc * 4] = o;
    }

    s16x8 bfrag[NT][4];
#pragma unroll
    for (int i = 0; i < NT; i++) {
        int colg = (w * NT + i) * 16 + cl;
#pragma unroll
        for (int s = 0; s < 4; s++)
#pragma unroll
            for (int j = 0; j < 8; j++)
                bfrag[i][s][j] = (short)f2bf(W[(s * 32 + kk * 8 + j) * NOUT + colg]);
    }

    __syncthreads();

    f32x4 acc[4][NT];
#pragma unroll
    for (int rt = 0; rt < 4; rt++)
#pragma unroll
        for (int i = 0; i < NT; i++) acc[rt][i] = (f32x4){0.f, 0.f, 0.f, 0.f};

#pragma unroll
    for (int rt = 0; rt < 4; rt++) {
        const int rl = rt * 16 + cl;
        s16x8 a[4];
#pragma unroll
        for (int s = 0; s < 4; s++)
            a[s] = *(const s16x8*)&Xl[rl * SP + s * 32 + kk * 8];
#pragma unroll
        for (int i = 0; i < NT; i++)
#pragma unroll
            for (int s = 0; s < 4; s++)
                acc[rt][i] = __builtin_amdgcn_mfma_f32_16x16x32_bf16(a[s], bfrag[i][s],
                                                                     acc[rt][i], 0, 0, 0);
    }

#pragma unroll
    for (int rt = 0; rt < 4; rt++) {
        float dvv[4] = {1.f, 1.f, 1.f, 1.f};
        if (PRESCALE) {
            float4 dv = *(const float4*)&dinv[row0 + rt * 16 + kk * 4];
            dvv[0] = dv.x; dvv[1] = dv.y; dvv[2] = dv.z; dvv[3] = dv.w;
        }
#pragma unroll
        for (int i = 0; i < NT; i++) {
            int colg = (w * NT + i) * 16 + cl;
#pragma unroll
            for (int r = 0; r < 4; r++) {
                int rowg = row0 + rt * 16 + kk * 4 + r;
                if (rowg < N_NODES)
                    H[(size_t)rowg * NOUT + colg] = f2bf(dvv[r] * acc[rt][i][r]);
            }
        }
    }
}

// ---------------- agg layer 1 (128 ch, UNSCALED h1): 1 node/wave, per-edge dinv ----------------
// out[n][c] = relu( dinv[n]*( dinv[n]*h1[n][c] + sum_s dinv[s]*h1[s][c] ) + b[c] )
// Half-wave edge split: 32 lanes x uint2 (8B) cover a 256B row; halves alternate 4-edge batches.

__global__ __launch_bounds__(256) void agg128_kernel(const int* __restrict__ rowptr,
                                                     const int* __restrict__ csr,
                                                     const float* __restrict__ dinv,
                                                     const uint2* __restrict__ H,
                                                     const float* __restrict__ b,
                                                     uint2* __restrict__ out) {
    const int node = blockIdx.x * 4 + (threadIdx.x >> 6);
    const int half = (threadIdx.x >> 5) & 1;
    const int q = threadIdx.x & 31;

    float a0 = 0.f, a1 = 0.f, a2 = 0.f, a3 = 0.f;
    const int e0 = rowptr[node];
    const int cnt = rowptr[node + 1] - e0;
    const int base = e0 + half * 4;

    int k = 0;
    for (; k + 8 <= cnt; k += 8) {  // 8 edges/iter, 4 per half
        int i0 = csr[base + k];
        int i1 = csr[base + k + 1];
        int i2 = csr[base + k + 2];
        int i3 = csr[base + k + 3];
        float d0 = dinv[i0], d1 = dinv[i1], d2 = dinv[i2], d3 = dinv[i3];
        uint2 h0 = H[(size_t)i0 * 32 + q];
        uint2 h1v = H[(size_t)i1 * 32 + q];
        uint2 h2v = H[(size_t)i2 * 32 + q];
        uint2 h3v = H[(size_t)i3 * 32 + q];
        a0 = fmaf(d0, bf2f((unsigned short)(h0.x & 0xffff)), a0);
        a1 = fmaf(d0, bf2f((unsigned short)(h0.x >> 16)), a1);
        a2 = fmaf(d0, bf2f((unsigned short)(h0.y & 0xffff)), a2);
        a3 = fmaf(d0, bf2f((unsigned short)(h0.y >> 16)), a3);
        a0 = fmaf(d1, bf2f((unsigned short)(h1v.x & 0xffff)), a0);
        a1 = fmaf(d1, bf2f((unsigned short)(h1v.x >> 16)), a1);
        a2 = fmaf(d1, bf2f((unsigned short)(h1v.y & 0xffff)), a2);
        a3 = fmaf(d1, bf2f((unsigned short)(h1v.y >> 16)), a3);
        a0 = fmaf(d2, bf2f((unsigned short)(h2v.x & 0xffff)), a0);
        a1 = fmaf(d2, bf2f((unsigned short)(h2v.x >> 16)), a1);
        a2 = fmaf(d2, bf2f((unsigned short)(h2v.y & 0xffff)), a2);
        a3 = fmaf(d2, bf2f((unsigned short)(h2v.y >> 16)), a3);
        a0 = fmaf(d3, bf2f((unsigned short)(h3v.x & 0xffff)), a0);
        a1 = fmaf(d3, bf2f((unsigned short)(h3v.x >> 16)), a1);
        a2 = fmaf(d3, bf2f((unsigned short)(h3v.y & 0xffff)), a2);
        a3 = fmaf(d3, bf2f((unsigned short)(h3v.y >> 16)), a3);
    }
    for (int j = k + half; j < cnt; j += 2) {  // tail: 2 edges/iter (1 per half)
        int s = csr[e0 + j];
        float ds = dinv[s];
        uint2 h = H[(size_t)s * 32 + q];
        a0 = fmaf(ds, bf2f((unsigned short)(h.x & 0xffff)), a0);
        a1 = fmaf(ds, bf2f((unsigned short)(h.x >> 16)), a1);
        a2 = fmaf(ds, bf2f((unsigned short)(h.y & 0xffff)), a2);
        a3 = fmaf(ds, bf2f((unsigned short)(h.y >> 16)), a3);
    }

    a0 += __shfl_xor(a0, 32);
    a1 += __shfl_xor(a1, 32);
    a2 += __shfl_xor(a2, 32);
    a3 += __shfl_xor(a3, 32);

    if (half == 0) {
        const float dn = dinv[node];
        uint2 self = H[(size_t)node * 32 + q];
        float4 bb = *(const float4*)&b[q * 4];
        float r0 = fmaf(dn, fmaf(dn, bf2f((unsigned short)(self.x & 0xffff)), a0), bb.x);
        float r1 = fmaf(dn, fmaf(dn, bf2f((unsigned short)(self.x >> 16)), a1), bb.y);
        float r2 = fmaf(dn, fmaf(dn, bf2f((unsigned short)(self.y & 0xffff)), a2), bb.z);
        float r3 = fmaf(dn, fmaf(dn, bf2f((unsigned short)(self.y >> 16)), a3), bb.w);
        r0 = fmaxf(r0, 0.f);
        r1 = fmaxf(r1, 0.f);
        r2 = fmaxf(r2, 0.f);
        r3 = fmaxf(r3, 0.f);
        uint2 o;
        o.x = (unsigned int)f2bf(r0) | ((unsigned int)f2bf(r1) << 16);
        o.y = (unsigned int)f2bf(r2) | ((unsigned int)f2bf(r3) << 16);
        out[(size_t)node * 32 + q] = o;
    }
}

// ---------------- agg layer 2 (64 ch, h3 PRE-SCALED): 1 node/wave, fp32 out ----------------

__global__ __launch_bounds__(256) void agg64_kernel(const int* __restrict__ rowptr,
                                                    const int* __restrict__ csr,
                                                    const float* __restrict__ dinv,
                                                    const unsigned int* __restrict__ H,
                                                    const float* __restrict__ b,
                                                    float2* __restrict__ out) {
    const int node = blockIdx.x * 4 + (threadIdx.x >> 6);
    const int half = (threadIdx.x >> 5) & 1;
    const int q = threadIdx.x & 31;

    float a0 = 0.f, a1 = 0.f;
    const int e0 = rowptr[node];
    const int cnt = rowptr[node + 1] - e0;
    const int base = e0 + half * 4;

    int k = 0;
    for (; k + 8 <= cnt; k += 8) {
        int i0 = csr[base + k];
        int i1 = csr[base + k + 1];
        int i2 = csr[base + k + 2];
        int i3 = csr[base + k + 3];
        unsigned int h0 = H[(size_t)i0 * 32 + q];
        unsigned int h1 = H[(size_t)i1 * 32 + q];
        unsigned int h2 = H[(size_t)i2 * 32 + q];
        unsigned int h3 = H[(size_t)i3 * 32 + q];
        a0 += bf2f((unsigned short)(h0 & 0xffff)) + bf2f((unsigned short)(h1 & 0xffff)) +
              bf2f((unsigned short)(h2 & 0xffff)) + bf2f((unsigned short)(h3 & 0xffff));
        a1 += bf2f((unsigned short)(h0 >> 16)) + bf2f((unsigned short)(h1 >> 16)) +
              bf2f((unsigned short)(h2 >> 16)) + bf2f((unsigned short)(h3 >> 16));
    }
    for (int j = k + half; j < cnt; j += 2) {
        int s = csr[e0 + j];
        unsigned int h = H[(size_t)s * 32 + q];
        a0 += bf2f((unsigned short)(h & 0xffff));
        a1 += bf2f((unsigned short)(h >> 16));
    }

    a0 += __shfl_xor(a0, 32);
    a1 += __shfl_xor(a1, 32);

    if (half == 0) {
        const float dn = dinv[node];
        unsigned int self = H[(size_t)node * 32 + q];
        float2 bb = *(const float2*)&b[q * 2];
        float r0 = fmaf(dn, bf2f((unsigned short)(self & 0xffff)) + a0, bb.x);
        float r1 = fmaf(dn, bf2f((unsigned short)(self >> 16)) + a1, bb.y);
        out[(size_t)node * 32 + q] = make_float2(r0, r1);
    }
}

// ---------------- launch ----------------

extern "C" void kernel_launch(void* const* d_in, const int* in_sizes, int n_in,
                              void* d_out, int out_size, void* d_ws, size_t ws_size,
                              hipStream_t stream) {
    const float* x  = (const float*)d_in[0];
    const int*   ei = (const int*)d_in[1];
    const float* W1 = (const float*)d_in[2];
    const float* b1 = (const float*)d_in[3];
    const float* W2 = (const float*)d_in[4];
    const float* b2 = (const float*)d_in[5];

    const int* src = ei;
    const int* dst = ei + N_EDGES;

    // workspace layout
    unsigned short* h1 = (unsigned short*)d_ws;                 // [N][128] bf16 (UNSCALED h1 / h3)
    unsigned short* h2 = h1 + (size_t)N_NODES * HID_C;          // [N][128] bf16 activations
    float* dinv   = (float*)(h2 + (size_t)N_NODES * HID_C);     // 50,048 f
    int*   degi   = (int*)(dinv + 50048);                       // 50,048 i (deg -> cursor)
    int*   rowptr = degi + 50048;                               // 50,001 i
    int*   csr    = rowptr + 50051;                             // 500,000 i
    int*   bsum   = csr + 500000;                               // 256 i
    unsigned short* h3 = h1;                                    // reuse h1: [N][64] bf16

    // 1) zero degree array (200KB)
    {
        int n4 = (N_NODES + 3) / 4;
        zero_kernel<<<(n4 + 255) / 256, 256, 0, stream>>>((int4*)degi, n4);
    }

    // 2) GEMM1 (unscaled h1) FUSED with degree histogram (role-split, independent work)
    mfma_gemm<HID_C, false, false, true><<<NTILES + DEGB, 256, 0, stream>>>(
        x, W1, nullptr, h1, dst, degi);

    // 3-5) CSR build
    scan1_kernel<<<SCAN_NB, 256, 0, stream>>>(degi, rowptr, bsum, dinv);
    scan23_kernel<<<SCAN_NB, 256, 0, stream>>>(rowptr, degi, bsum);
    fill_kernel<<<(N_EDGES + 255) / 256, 256, 0, stream>>>(src, dst, degi, csr);

    // 6) agg layer 1 (per-edge dinv) -> h2
    agg128_kernel<<<N_NODES / 4, 256, 0, stream>>>(rowptr, csr, dinv, (const uint2*)h1, b1,
                                                   (uint2*)h2);

    // 7) GEMM2 (prescaled by dinv) -> h3
    mfma_gemm<OUT_C, true, true, false><<<NTILES, 256, 0, stream>>>(
        h2, W2, dinv, h3, nullptr, nullptr);

    // 8) agg layer 2 -> out (fp32)
    agg64_kernel<<<N_NODES / 4, 256, 0, stream>>>(rowptr, csr, dinv, (const unsigned int*)h3,
                                                  b2, (float2*)d_out);
}